// Round 7
// baseline (429.430 us; speedup 1.0000x reference)
//
#include <hip/hip_runtime.h>

#define NDATA 500000
#define EMB   256
#define BS    64
#define KP1   4097            // K+1
#define NPAIR (BS * KP1)      // 262208
#define INV_T (1.0f / 0.07f)

#define SCAN_EPB 2048
#define NB_SCAN  ((NDATA + SCAN_EPB - 1) / SCAN_EPB)   // 245
#define RPW      32                                     // rows per wave (fused)
#define NWAVES   (NDATA / RPW)                          // 15625 exactly
#define NBLKF    ((NWAVES + 3) / 4)                     // 3907 blocks per z
#define SSC_BLKS ((NPAIR + 255) / 256)                  // 1025
#define SCALE_BLKS ((2 * NPAIR + 255) / 256)            // 2049 (fallback)
#define NBY      17                                     // fallback k-chunks

typedef float    f32x4 __attribute__((ext_vector_type(4)));
typedef unsigned u32x4 __attribute__((ext_vector_type(4)));

// ---------------- normalize (blocks 0..127) + histogram (rest) ---------------
__global__ __launch_bounds__(256) void norm_hist_kernel(
    const float* __restrict__ vis_feat, const float* __restrict__ text_feat,
    float* __restrict__ vn, float* __restrict__ tn,
    const int* __restrict__ slct, unsigned* __restrict__ counts,
    unsigned* __restrict__ old) {
  int bid = blockIdx.x;
  if (bid < 128) {
    int b = bid & 63;
    bool is_vis = bid < 64;
    const float* src = (is_vis ? vis_feat : text_feat) + b * EMB;
    float* dst = (is_vis ? vn : tn) + b * EMB;
    int t = threadIdx.x;
    float x = src[t];
    float s = x * x;
    for (int off = 32; off > 0; off >>= 1) s += __shfl_down(s, off, 64);
    __shared__ float red[4];
    if ((t & 63) == 0) red[t >> 6] = s;
    __syncthreads();
    float norm = sqrtf(red[0] + red[1] + red[2] + red[3]);
    dst[t] = x / fmaxf(norm, 1e-12f);
  } else {
    int i = (bid - 128) * 256 + threadIdx.x;
    if (i < NPAIR) {
      int r = slct[i];
      old[i] = atomicAdd(&counts[r], 1u);
    }
  }
}

// ---------------- scan pass 1: per-block exclusive scan + block sums ---------
__global__ __launch_bounds__(256) void scan1_kernel(
    const unsigned* __restrict__ counts, unsigned* __restrict__ start,
    unsigned* __restrict__ bsum) {
  int t = threadIdx.x;
  int base = blockIdx.x * SCAN_EPB + t * 8;
  unsigned v[8];
  unsigned tsum = 0;
#pragma unroll
  for (int j = 0; j < 8; ++j) {
    int i = base + j;
    unsigned c = (i < NDATA) ? counts[i] : 0u;
    v[j] = tsum;
    tsum += c;
  }
  unsigned x = tsum;
  for (int d = 1; d < 64; d <<= 1) {
    unsigned y = __shfl_up(x, d, 64);
    if ((t & 63) >= d) x += y;
  }
  __shared__ unsigned wsum[4];
  if ((t & 63) == 63) wsum[t >> 6] = x;
  __syncthreads();
  unsigned woff = 0;
  for (int wv = 0; wv < (t >> 6); ++wv) woff += wsum[wv];
  unsigned ex = woff + x - tsum;
#pragma unroll
  for (int j = 0; j < 8; ++j) {
    int i = base + j;
    if (i < NDATA) start[i] = ex + v[j];
  }
  if (t == 255) bsum[blockIdx.x] = woff + x;
}

// ------ scatter (+ redundant in-block scan of bsum; block 0 publishes) -------
__global__ __launch_bounds__(256) void scatter2_kernel(
    const int* __restrict__ slct, const unsigned* __restrict__ start,
    const unsigned* __restrict__ bsum, const unsigned* __restrict__ old,
    unsigned* __restrict__ pairs, unsigned* __restrict__ bsum2) {
  __shared__ unsigned sbs[256];
  __shared__ unsigned wsum[4];
  int t = threadIdx.x;
  unsigned v = (t < NB_SCAN) ? bsum[t] : 0u;
  unsigned x = v;
  for (int d = 1; d < 64; d <<= 1) {
    unsigned y = __shfl_up(x, d, 64);
    if ((t & 63) >= d) x += y;
  }
  if ((t & 63) == 63) wsum[t >> 6] = x;
  __syncthreads();
  unsigned woff = 0;
  for (int wv = 0; wv < (t >> 6); ++wv) woff += wsum[wv];
  sbs[t] = woff + x - v;          // exclusive scan of block sums
  __syncthreads();
  if (blockIdx.x == 0) bsum2[t] = sbs[t];
  int i = blockIdx.x * 256 + t;
  if (i < NPAIR) {
    int r = slct[i];
    unsigned pos = start[r] + sbs[r >> 11] + old[i];
    int b = i / KP1;              // magic-mul division
    int kk = i - b * KP1;
    pairs[pos] = ((unsigned)b << 13) | (unsigned)kk;
  }
}

// ---------------- fused bank copy + gathered dot/exp -------------------------
#define LOADC(R, rb)                                                          \
  { _Pragma("unroll") for (int j = 0; j < 8; ++j)                             \
      R[j] = __builtin_nontemporal_load(&s4[(size_t)((rb) + j) * 64 + lane]); }

#define STOREC(R, rb)                                                         \
  { _Pragma("unroll") for (int j = 0; j < 8; ++j)                             \
      __builtin_nontemporal_store(R[j], &d4[(size_t)((rb) + j) * 64 + lane]); }

#define DOT4(Rj, fv) (Rj.x * fv.x + Rj.y * fv.y + Rj.z * fv.z + Rj.w * fv.w)

// chunk-batched refs: ONE pairs-wait and ONE feat-wait per u-level per chunk,
// instead of per-ref dependent chains (each of which drains the vmcnt queue).
__device__ __forceinline__ void refs_chunk(
    const f32x4* R, int rb, unsigned bso,
    const unsigned* __restrict__ counts, const unsigned* __restrict__ start,
    const unsigned* __restrict__ pairs, const f32x4* __restrict__ f4,
    float* __restrict__ tz, int lane, float& local) {
  u32x4 c0 = *(const u32x4*)&counts[rb];
  u32x4 c1 = *(const u32x4*)&counts[rb + 4];
  u32x4 s0 = *(const u32x4*)&start[rb];
  u32x4 s1 = *(const u32x4*)&start[rb + 4];
  unsigned cn[8] = {c0.x, c0.y, c0.z, c0.w, c1.x, c1.y, c1.z, c1.w};
  unsigned sn[8] = {s0.x, s0.y, s0.z, s0.w, s1.x, s1.y, s1.z, s1.w};
  unsigned gsb[8];
  unsigned maxn = 0;
#pragma unroll
  for (int j = 0; j < 8; ++j) {
    gsb[j] = sn[j] + bso;
    maxn = maxn > cn[j] ? maxn : cn[j];
  }
  for (unsigned u = 0; u < maxn; ++u) {   // wave-uniform loop, usually 1-2 iters
    unsigned pp[8];
    f32x4 fv[8];
    float d[8];
#pragma unroll
    for (int j = 0; j < 8; ++j)
      if (cn[j] > u) pp[j] = pairs[gsb[j] + u];      // all issued, one wait
#pragma unroll
    for (int j = 0; j < 8; ++j)
      if (cn[j] > u) fv[j] = f4[(pp[j] >> 13) * 64 + lane];  // all issued, one wait
#pragma unroll
    for (int j = 0; j < 8; ++j)
      d[j] = (cn[j] > u) ? DOT4(R[j], fv[j]) : 0.f;
#pragma unroll
    for (int off = 32; off > 0; off >>= 1) {         // 8-wide ILP butterfly
      d[0] += __shfl_down(d[0], off, 64);
      d[1] += __shfl_down(d[1], off, 64);
      d[2] += __shfl_down(d[2], off, 64);
      d[3] += __shfl_down(d[3], off, 64);
      d[4] += __shfl_down(d[4], off, 64);
      d[5] += __shfl_down(d[5], off, 64);
      d[6] += __shfl_down(d[6], off, 64);
      d[7] += __shfl_down(d[7], off, 64);
    }
    if (lane == 0) {
#pragma unroll
      for (int j = 0; j < 8; ++j)
        if (cn[j] > u) {
          float e = __expf(d[j] * INV_T);
          tz[gsb[j] + u] = e;
          local += e;
        }
    }
  }
}

__global__ __launch_bounds__(256) void fused_copy_dot_kernel(
    const float* __restrict__ text_mem, const float* __restrict__ vis_mem,
    float* __restrict__ out_text, float* __restrict__ out_vis,
    const float* __restrict__ vn, const float* __restrict__ tn,
    const unsigned* __restrict__ counts, const unsigned* __restrict__ start,
    const unsigned* __restrict__ bsum2, const unsigned* __restrict__ pairs,
    float* __restrict__ tmp0, float* __restrict__ tmp1,
    float* __restrict__ zsum) {
  int z = blockIdx.z;
  const f32x4* s4 = (const f32x4*)(z == 0 ? text_mem : vis_mem);
  f32x4* d4 = (f32x4*)(z == 0 ? out_text : out_vis);
  const f32x4* f4 = (const f32x4*)(z == 0 ? vn : tn);
  float* tz = (z == 0) ? tmp0 : tmp1;

  int t = threadIdx.x, w = t >> 6, lane = t & 63;
  int gw = blockIdx.x * 4 + w;
  float local = 0.f;

  if (gw < NWAVES) {
    int r0 = gw * RPW;
    unsigned bso = bsum2[r0 >> 11];  // 32-row wave never crosses a scan block
    f32x4 A[8], B[8];
    LOADC(A, r0);
    LOADC(B, r0 + 8);                // 16 KB in flight before first store
    STOREC(A, r0);
    refs_chunk(A, r0, bso, counts, start, pairs, f4, tz, lane, local);
    LOADC(A, r0 + 16);
    STOREC(B, r0 + 8);
    refs_chunk(B, r0 + 8, bso, counts, start, pairs, f4, tz, lane, local);
    LOADC(B, r0 + 24);
    STOREC(A, r0 + 16);
    refs_chunk(A, r0 + 16, bso, counts, start, pairs, f4, tz, lane, local);
    STOREC(B, r0 + 24);
    refs_chunk(B, r0 + 24, bso, counts, start, pairs, f4, tz, lane, local);
  }
  __shared__ float red[4];
  if (lane == 0) red[w] = local;
  __syncthreads();
  if (t == 0) {
    float s = red[0] + red[1] + red[2] + red[3];
    atomicAdd(&zsum[z], s);
  }
}

// ------- scatter-scale (blocks < SSC_BLKS): out[b,k] = tmp[pos]/Z; + EMA -----
__global__ __launch_bounds__(256) void scatter_scale_update_kernel(
    const unsigned* __restrict__ pairs,
    const float* __restrict__ tmp0, const float* __restrict__ tmp1,
    float* __restrict__ out, const float* __restrict__ zsum,
    const float* __restrict__ vis_mem, const float* __restrict__ text_mem,
    const float* __restrict__ vn, const float* __restrict__ tn,
    const int* __restrict__ idx,
    float* __restrict__ out_vis, float* __restrict__ out_text) {
  int bid = blockIdx.x;
  if (bid < SSC_BLKS) {
    int pos = bid * 256 + threadIdx.x;
    if (pos < NPAIR) {
      const float c = (float)NDATA / (float)NPAIR;
      unsigned p = pairs[pos];
      int o = (int)(p >> 13) * KP1 + (int)(p & 8191u);
      out[o]         = tmp0[pos] / (zsum[0] * c);
      out[NPAIR + o] = tmp1[pos] / (zsum[1] * c);
    }
  } else {
    int bb = bid - SSC_BLKS;       // 0..127
    int b = bb & 63;
    bool is_vis = bb < 64;
    int row = idx[b];
    for (int b2 = b + 1; b2 < BS; ++b2)   // last duplicate wins
      if (idx[b2] == row) return;
    const float* mem  = (is_vis ? vis_mem : text_mem) + (size_t)row * EMB;
    const float* feat = (is_vis ? vn : tn) + b * EMB;
    float* dst = (is_vis ? out_vis : out_text) + (size_t)row * EMB;
    int t = threadIdx.x;
    float p = mem[t] * 0.5f + feat[t] * 0.5f;   // M = 0.5
    float s = p * p;
    for (int off = 32; off > 0; off >>= 1) s += __shfl_down(s, off, 64);
    __shared__ float red[4];
    if ((t & 63) == 0) red[t >> 6] = s;
    __syncthreads();
    float norm = sqrtf(red[0] + red[1] + red[2] + red[3]);
    dst[t] = p / fmaxf(norm, 1e-12f);
  }
}

// ================= fallback (round-2 proven path) ============================
__global__ __launch_bounds__(256) void dot_exp_kernel(
    const float* __restrict__ text_mem, const float* __restrict__ vis_mem,
    const float* __restrict__ vn, const float* __restrict__ tn,
    const int* __restrict__ slct, float* __restrict__ out,
    float* __restrict__ partials) {
  int b = blockIdx.x;
  int z = blockIdx.z;
  const float* mem  = (z == 0) ? text_mem : vis_mem;
  const float* feat = (z == 0) ? vn : tn;
  float* o = out + (size_t)z * NPAIR + (size_t)b * KP1;
  const int* srow = slct + b * KP1;
  __shared__ float4 sf[64];
  int t = threadIdx.x;
  if (t < 64) sf[t] = ((const float4*)(feat + b * EMB))[t];
  __syncthreads();
  int w = t >> 6, lane = t & 63;
  float4 f = sf[lane];
  int kbase = blockIdx.y * 256 + w * 64;
  int kend  = min(kbase + 64, KP1);
  float local = 0.f;
  int k = kbase;
  for (; k + 2 <= kend; k += 2) {
    int r0 = srow[k], r1 = srow[k + 1];
    float4 v0 = ((const float4*)(mem + (size_t)r0 * EMB))[lane];
    float4 v1 = ((const float4*)(mem + (size_t)r1 * EMB))[lane];
    float p0 = v0.x * f.x + v0.y * f.y + v0.z * f.z + v0.w * f.w;
    float p1 = v1.x * f.x + v1.y * f.y + v1.z * f.z + v1.w * f.w;
    for (int off = 32; off > 0; off >>= 1) {
      p0 += __shfl_down(p0, off, 64);
      p1 += __shfl_down(p1, off, 64);
    }
    if (lane == 0) {
      float e0 = __expf(p0 * INV_T);
      float e1 = __expf(p1 * INV_T);
      o[k] = e0; o[k + 1] = e1;
      local += e0 + e1;
    }
  }
  if (k < kend) {
    int r0 = srow[k];
    float4 v0 = ((const float4*)(mem + (size_t)r0 * EMB))[lane];
    float p0 = v0.x * f.x + v0.y * f.y + v0.z * f.z + v0.w * f.w;
    for (int off = 32; off > 0; off >>= 1) p0 += __shfl_down(p0, off, 64);
    if (lane == 0) { float e0 = __expf(p0 * INV_T); o[k] = e0; local += e0; }
  }
  __shared__ float red[4];
  if (lane == 0) red[w] = local;
  __syncthreads();
  if (t == 0)
    partials[((size_t)z * NBY + blockIdx.y) * BS + b] =
        red[0] + red[1] + red[2] + red[3];
}

__global__ __launch_bounds__(256) void reduce_z_kernel(
    const float* __restrict__ partials, float* __restrict__ zsum, int per_z) {
  int z = blockIdx.x;
  const float* p = partials + (size_t)z * per_z;
  float s = 0.f;
  for (int i = threadIdx.x; i < per_z; i += 256) s += p[i];
  for (int off = 32; off > 0; off >>= 1) s += __shfl_down(s, off, 64);
  __shared__ float red[4];
  if ((threadIdx.x & 63) == 0) red[threadIdx.x >> 6] = s;
  __syncthreads();
  if (threadIdx.x == 0) zsum[z] = red[0] + red[1] + red[2] + red[3];
}

__global__ __launch_bounds__(256) void copy2_kernel(
    const float4* __restrict__ src_a, float4* __restrict__ dst_a,
    const float4* __restrict__ src_b, float4* __restrict__ dst_b, long n4) {
  long i = (long)blockIdx.x * blockDim.x + threadIdx.x;
  long stride = (long)gridDim.x * blockDim.x;
  for (; i < 2 * n4; i += stride) {
    if (i < n4) dst_a[i] = src_a[i];
    else        dst_b[i - n4] = src_b[i - n4];
  }
}

// fallback in-place scale + EMA update
__global__ __launch_bounds__(256) void scale_update_kernel(
    float* __restrict__ out, const float* __restrict__ zsum,
    const float* __restrict__ vis_mem, const float* __restrict__ text_mem,
    const float* __restrict__ vn, const float* __restrict__ tn,
    const int* __restrict__ idx,
    float* __restrict__ out_vis, float* __restrict__ out_text) {
  int bid = blockIdx.x;
  if (bid < SCALE_BLKS) {
    int i = bid * 256 + threadIdx.x;
    if (i < 2 * NPAIR) {
      float Z = ((i < NPAIR) ? zsum[0] : zsum[1]) * ((float)NDATA / (float)NPAIR);
      out[i] = out[i] / Z;
    }
  } else {
    int bb = bid - SCALE_BLKS;
    int b = bb & 63;
    bool is_vis = bb < 64;
    int row = idx[b];
    for (int b2 = b + 1; b2 < BS; ++b2)
      if (idx[b2] == row) return;
    const float* mem  = (is_vis ? vis_mem : text_mem) + (size_t)row * EMB;
    const float* feat = (is_vis ? vn : tn) + b * EMB;
    float* dst = (is_vis ? out_vis : out_text) + (size_t)row * EMB;
    int t = threadIdx.x;
    float p = mem[t] * 0.5f + feat[t] * 0.5f;
    float s = p * p;
    for (int off = 32; off > 0; off >>= 1) s += __shfl_down(s, off, 64);
    __shared__ float red[4];
    if ((t & 63) == 0) red[t >> 6] = s;
    __syncthreads();
    float norm = sqrtf(red[0] + red[1] + red[2] + red[3]);
    dst[t] = p / fmaxf(norm, 1e-12f);
  }
}

// =============================================================================
extern "C" void kernel_launch(void* const* d_in, const int* in_sizes, int n_in,
                              void* d_out, int out_size, void* d_ws, size_t ws_size,
                              hipStream_t stream) {
  const float* vis_feat  = (const float*)d_in[0];
  const float* text_feat = (const float*)d_in[1];
  const float* vis_mem   = (const float*)d_in[2];
  const float* text_mem  = (const float*)d_in[3];
  const int*   slct      = (const int*)d_in[4];
  const int*   idx       = (const int*)d_in[5];

  float* out          = (float*)d_out;
  float* out_vis_mem  = out + (size_t)2 * NPAIR;
  float* out_text_mem = out_vis_mem + (size_t)NDATA * EMB;

  // workspace layout: zsum|counts contiguous (one memset); 16B alignment kept
  float*    ws     = (float*)d_ws;
  float*    zsum   = ws;                                   // 4 (padded)
  unsigned* counts = (unsigned*)(zsum + 4);                // NDATA
  unsigned* start  = counts + NDATA;                       // NDATA
  unsigned* bsum   = start + NDATA;                        // 256
  unsigned* bsum2  = bsum + 256;                           // 256 (scanned)
  unsigned* old    = bsum2 + 256;                          // NPAIR (reused: tmp0)
  unsigned* pairs  = old + NPAIR;                          // NPAIR
  float*    tmp1   = (float*)(pairs + NPAIR);              // NPAIR
  float*    vn     = tmp1 + NPAIR;                         // 16384
  float*    tn     = vn + BS * EMB;                        // 16384
  float*    tmp0   = (float*)old;                          // alias (old dead after scatter)
  size_t needed = ((size_t)(4 + 2 * NDATA + 512 + 3 * NPAIR) +
                   (size_t)(2 * BS * EMB)) * 4;

  if (ws_size >= needed) {
    // ---- fused path ----
    hipMemsetAsync(zsum, 0, (4 + NDATA) * sizeof(unsigned), stream);
    norm_hist_kernel<<<128 + (NPAIR + 255) / 256, 256, 0, stream>>>(
        vis_feat, text_feat, vn, tn, slct, counts, old);
    scan1_kernel<<<NB_SCAN, 256, 0, stream>>>(counts, start, bsum);
    scatter2_kernel<<<SSC_BLKS, 256, 0, stream>>>(slct, start, bsum, old, pairs,
                                                  bsum2);

    dim3 gF(NBLKF, 1, 2);
    fused_copy_dot_kernel<<<gF, 256, 0, stream>>>(
        text_mem, vis_mem, out_text_mem, out_vis_mem, vn, tn,
        counts, start, bsum2, pairs, tmp0, tmp1, zsum);

    scatter_scale_update_kernel<<<SSC_BLKS + 128, 256, 0, stream>>>(
        pairs, tmp0, tmp1, out, zsum, vis_mem, text_mem, vn, tn, idx,
        out_vis_mem, out_text_mem);
  } else {
    // ---- fallback: proven round-2 path ----
    norm_hist_kernel<<<128, 256, 0, stream>>>(
        vis_feat, text_feat, vn, tn, slct, counts, old);
    dim3 gB(BS, NBY, 2);
    dot_exp_kernel<<<gB, 256, 0, stream>>>(text_mem, vis_mem, vn, tn, slct, out,
                                           (float*)old);
    reduce_z_kernel<<<2, 256, 0, stream>>>((float*)old, zsum, NBY * BS);
    const long n4 = (long)NDATA * EMB / 4;
    copy2_kernel<<<8192, 256, 0, stream>>>(
        (const float4*)vis_mem,  (float4*)out_vis_mem,
        (const float4*)text_mem, (float4*)out_text_mem, n4);
    scale_update_kernel<<<SCALE_BLKS + 128, 256, 0, stream>>>(
        out, zsum, vis_mem, text_mem, vn, tn, idx, out_vis_mem, out_text_mem);
  }
}

// Round 8
// 410.033 us; speedup vs baseline: 1.0473x; 1.0473x over previous
//
#include <hip/hip_runtime.h>

#define NDATA 500000
#define EMB   256
#define BS    64
#define KP1   4097            // K+1
#define NPAIR (BS * KP1)      // 262208
#define INV_T (1.0f / 0.07f)

#define SCAN_EPB 2048
#define NB_SCAN  ((NDATA + SCAN_EPB - 1) / SCAN_EPB)   // 245
#define RPW      32                                     // rows per wave (fused)
#define NWAVES   (NDATA / RPW)                          // 15625 exactly
#define NBLKF    ((NWAVES + 3) / 4)                     // 3907 blocks per z
#define SSC_BLKS ((NPAIR + 255) / 256)                  // 1025
#define SCALE_BLKS ((2 * NPAIR + 255) / 256)            // 2049 (fallback)
#define NBY      17                                     // fallback k-chunks

typedef float    f32x4 __attribute__((ext_vector_type(4)));
typedef unsigned u32x4 __attribute__((ext_vector_type(4)));

// ---------------- DPP 64-lane sum: 6 VALU-rate ops, result in lane 63 --------
template <int CTRL, int RMASK>
__device__ __forceinline__ float dpp_add(float x) {
  int y = __builtin_amdgcn_update_dpp(0, __float_as_int(x), CTRL, RMASK, 0xf,
                                      false);
  return x + __int_as_float(y);
}
__device__ __forceinline__ float wave_sum_dpp(float x) {
  x = dpp_add<0x111, 0xf>(x);   // row_shr:1
  x = dpp_add<0x112, 0xf>(x);   // row_shr:2
  x = dpp_add<0x114, 0xf>(x);   // row_shr:4
  x = dpp_add<0x118, 0xf>(x);   // row_shr:8
  x = dpp_add<0x142, 0xa>(x);   // row_bcast:15 -> rows 1,3
  x = dpp_add<0x143, 0xc>(x);   // row_bcast:31 -> rows 2,3
  return x;                     // lane 63 holds the full sum
}

// ---------------- normalize (blocks 0..127) + histogram (rest) ---------------
__global__ __launch_bounds__(256) void norm_hist_kernel(
    const float* __restrict__ vis_feat, const float* __restrict__ text_feat,
    float* __restrict__ vn, float* __restrict__ tn,
    const int* __restrict__ slct, unsigned* __restrict__ counts,
    unsigned* __restrict__ old) {
  int bid = blockIdx.x;
  if (bid < 128) {
    int b = bid & 63;
    bool is_vis = bid < 64;
    const float* src = (is_vis ? vis_feat : text_feat) + b * EMB;
    float* dst = (is_vis ? vn : tn) + b * EMB;
    int t = threadIdx.x;
    float x = src[t];
    float s = x * x;
    for (int off = 32; off > 0; off >>= 1) s += __shfl_down(s, off, 64);
    __shared__ float red[4];
    if ((t & 63) == 0) red[t >> 6] = s;
    __syncthreads();
    float norm = sqrtf(red[0] + red[1] + red[2] + red[3]);
    dst[t] = x / fmaxf(norm, 1e-12f);
  } else {
    int i = (bid - 128) * 256 + threadIdx.x;
    if (i < NPAIR) {
      int r = slct[i];
      old[i] = atomicAdd(&counts[r], 1u);
    }
  }
}

// ---------------- scan pass 1: per-block exclusive scan + block sums ---------
__global__ __launch_bounds__(256) void scan1_kernel(
    const unsigned* __restrict__ counts, unsigned* __restrict__ start,
    unsigned* __restrict__ bsum) {
  int t = threadIdx.x;
  int base = blockIdx.x * SCAN_EPB + t * 8;
  unsigned v[8];
  unsigned tsum = 0;
#pragma unroll
  for (int j = 0; j < 8; ++j) {
    int i = base + j;
    unsigned c = (i < NDATA) ? counts[i] : 0u;
    v[j] = tsum;
    tsum += c;
  }
  unsigned x = tsum;
  for (int d = 1; d < 64; d <<= 1) {
    unsigned y = __shfl_up(x, d, 64);
    if ((t & 63) >= d) x += y;
  }
  __shared__ unsigned wsum[4];
  if ((t & 63) == 63) wsum[t >> 6] = x;
  __syncthreads();
  unsigned woff = 0;
  for (int wv = 0; wv < (t >> 6); ++wv) woff += wsum[wv];
  unsigned ex = woff + x - tsum;
#pragma unroll
  for (int j = 0; j < 8; ++j) {
    int i = base + j;
    if (i < NDATA) start[i] = ex + v[j];
  }
  if (t == 255) bsum[blockIdx.x] = woff + x;
}

// ------ scatter (+ redundant in-block scan of bsum; block 0 publishes) -------
__global__ __launch_bounds__(256) void scatter2_kernel(
    const int* __restrict__ slct, const unsigned* __restrict__ start,
    const unsigned* __restrict__ bsum, const unsigned* __restrict__ old,
    unsigned* __restrict__ pairs, unsigned* __restrict__ bsum2) {
  __shared__ unsigned sbs[256];
  __shared__ unsigned wsum[4];
  int t = threadIdx.x;
  unsigned v = (t < NB_SCAN) ? bsum[t] : 0u;
  unsigned x = v;
  for (int d = 1; d < 64; d <<= 1) {
    unsigned y = __shfl_up(x, d, 64);
    if ((t & 63) >= d) x += y;
  }
  if ((t & 63) == 63) wsum[t >> 6] = x;
  __syncthreads();
  unsigned woff = 0;
  for (int wv = 0; wv < (t >> 6); ++wv) woff += wsum[wv];
  sbs[t] = woff + x - v;          // exclusive scan of block sums
  __syncthreads();
  if (blockIdx.x == 0) bsum2[t] = sbs[t];
  int i = blockIdx.x * 256 + t;
  if (i < NPAIR) {
    int r = slct[i];
    unsigned pos = start[r] + sbs[r >> 11] + old[i];
    int b = i / KP1;              // magic-mul division
    int kk = i - b * KP1;
    pairs[pos] = ((unsigned)b << 13) | (unsigned)kk;
  }
}

// ---------------- fused bank copy + gathered dot/exp -------------------------
#define LOADC(R, rb)                                                          \
  { _Pragma("unroll") for (int j = 0; j < 8; ++j)                             \
      R[j] = __builtin_nontemporal_load(&s4[(size_t)((rb) + j) * 64 + lane]); }

#define STOREC(R, rb)                                                         \
  { _Pragma("unroll") for (int j = 0; j < 8; ++j)                             \
      __builtin_nontemporal_store(R[j], &d4[(size_t)((rb) + j) * 64 + lane]); }

#define DOT4(Rj, fv) (Rj.x * fv.x + Rj.y * fv.y + Rj.z * fv.z + Rj.w * fv.w)

// refs: R6 per-row 4-wide batches, but DPP reduce (result in lane 63)
#define REFS(R, rb)                                                           \
  { u32x4 c0 = *(const u32x4*)&counts[(rb)];                                  \
    u32x4 c1 = *(const u32x4*)&counts[(rb) + 4];                              \
    u32x4 s0 = *(const u32x4*)&start[(rb)];                                   \
    u32x4 s1 = *(const u32x4*)&start[(rb) + 4];                               \
    unsigned cn[8] = {c0.x, c0.y, c0.z, c0.w, c1.x, c1.y, c1.z, c1.w};        \
    unsigned sn[8] = {s0.x, s0.y, s0.z, s0.w, s1.x, s1.y, s1.z, s1.w};        \
    _Pragma("unroll") for (int j = 0; j < 8; ++j) {                           \
      unsigned n = cn[j];                                                     \
      if (n) {                                                                \
        unsigned gs = sn[j] + bs;                                             \
        unsigned u = 0;                                                       \
        for (; u + 4 <= n; u += 4) {                                          \
          unsigned p0 = pairs[gs + u],     p1 = pairs[gs + u + 1];            \
          unsigned p2 = pairs[gs + u + 2], p3 = pairs[gs + u + 3];            \
          f32x4 f0 = f4[(p0 >> 13) * 64 + lane];                              \
          f32x4 f1 = f4[(p1 >> 13) * 64 + lane];                              \
          f32x4 f2 = f4[(p2 >> 13) * 64 + lane];                              \
          f32x4 f3 = f4[(p3 >> 13) * 64 + lane];                              \
          float d0 = DOT4(R[j], f0), d1 = DOT4(R[j], f1);                     \
          float d2 = DOT4(R[j], f2), d3 = DOT4(R[j], f3);                     \
          d0 = wave_sum_dpp(d0); d1 = wave_sum_dpp(d1);                       \
          d2 = wave_sum_dpp(d2); d3 = wave_sum_dpp(d3);                       \
          if (lane == 63) {                                                   \
            float e0 = __expf(d0 * INV_T), e1 = __expf(d1 * INV_T);           \
            float e2 = __expf(d2 * INV_T), e3 = __expf(d3 * INV_T);           \
            tz[gs + u] = e0; tz[gs + u + 1] = e1;                             \
            tz[gs + u + 2] = e2; tz[gs + u + 3] = e3;                         \
            local += (e0 + e1) + (e2 + e3);                                   \
          }                                                                   \
        }                                                                     \
        for (; u < n; ++u) {                                                  \
          unsigned p = pairs[gs + u];                                         \
          f32x4 fv = f4[(p >> 13) * 64 + lane];                               \
          float d = DOT4(R[j], fv);                                           \
          d = wave_sum_dpp(d);                                                \
          if (lane == 63) {                                                   \
            float e = __expf(d * INV_T);                                      \
            tz[gs + u] = e;                                                   \
            local += e;                                                       \
          }                                                                   \
        }                                                                     \
      }                                                                       \
    } }

__global__ __launch_bounds__(256) void fused_copy_dot_kernel(
    const float* __restrict__ text_mem, const float* __restrict__ vis_mem,
    float* __restrict__ out_text, float* __restrict__ out_vis,
    const float* __restrict__ vn, const float* __restrict__ tn,
    const unsigned* __restrict__ counts, const unsigned* __restrict__ start,
    const unsigned* __restrict__ bsum2, const unsigned* __restrict__ pairs,
    float* __restrict__ tmp0, float* __restrict__ tmp1,
    float* __restrict__ zsum) {
  int z = blockIdx.z;
  const f32x4* s4 = (const f32x4*)(z == 0 ? text_mem : vis_mem);
  f32x4* d4 = (f32x4*)(z == 0 ? out_text : out_vis);
  const f32x4* f4 = (const f32x4*)(z == 0 ? vn : tn);
  float* tz = (z == 0) ? tmp0 : tmp1;

  int t = threadIdx.x, w = t >> 6, lane = t & 63;
  int gw = blockIdx.x * 4 + w;
  float local = 0.f;

  if (gw < NWAVES) {
    int r0 = gw * RPW;
    unsigned bs = bsum2[r0 >> 11];   // 32-row wave never crosses a scan block
    f32x4 A[8], B[8];
    LOADC(A, r0);
    LOADC(B, r0 + 8);                // 16 KB in flight before first store
    STOREC(A, r0);      REFS(A, r0);
    LOADC(A, r0 + 16);
    STOREC(B, r0 + 8);  REFS(B, r0 + 8);
    LOADC(B, r0 + 24);
    STOREC(A, r0 + 16); REFS(A, r0 + 16);
    STOREC(B, r0 + 24); REFS(B, r0 + 24);
  }
  __shared__ float red[4];
  if (lane == 63) red[w] = local;
  __syncthreads();
  if (t == 0) {
    float s = red[0] + red[1] + red[2] + red[3];
    atomicAdd(&zsum[z], s);
  }
}

// ------- scatter-scale (blocks < SSC_BLKS): out[b,k] = tmp[pos]/Z; + EMA -----
__global__ __launch_bounds__(256) void scatter_scale_update_kernel(
    const unsigned* __restrict__ pairs,
    const float* __restrict__ tmp0, const float* __restrict__ tmp1,
    float* __restrict__ out, const float* __restrict__ zsum,
    const float* __restrict__ vis_mem, const float* __restrict__ text_mem,
    const float* __restrict__ vn, const float* __restrict__ tn,
    const int* __restrict__ idx,
    float* __restrict__ out_vis, float* __restrict__ out_text) {
  int bid = blockIdx.x;
  if (bid < SSC_BLKS) {
    int pos = bid * 256 + threadIdx.x;
    if (pos < NPAIR) {
      const float c = (float)NDATA / (float)NPAIR;
      unsigned p = pairs[pos];
      int o = (int)(p >> 13) * KP1 + (int)(p & 8191u);
      out[o]         = tmp0[pos] / (zsum[0] * c);
      out[NPAIR + o] = tmp1[pos] / (zsum[1] * c);
    }
  } else {
    int bb = bid - SSC_BLKS;       // 0..127
    int b = bb & 63;
    bool is_vis = bb < 64;
    int row = idx[b];
    for (int b2 = b + 1; b2 < BS; ++b2)   // last duplicate wins
      if (idx[b2] == row) return;
    const float* mem  = (is_vis ? vis_mem : text_mem) + (size_t)row * EMB;
    const float* feat = (is_vis ? vn : tn) + b * EMB;
    float* dst = (is_vis ? out_vis : out_text) + (size_t)row * EMB;
    int t = threadIdx.x;
    float p = mem[t] * 0.5f + feat[t] * 0.5f;   // M = 0.5
    float s = p * p;
    for (int off = 32; off > 0; off >>= 1) s += __shfl_down(s, off, 64);
    __shared__ float red[4];
    if ((t & 63) == 0) red[t >> 6] = s;
    __syncthreads();
    float norm = sqrtf(red[0] + red[1] + red[2] + red[3]);
    dst[t] = p / fmaxf(norm, 1e-12f);
  }
}

// ================= fallback (round-2 proven path) ============================
__global__ __launch_bounds__(256) void dot_exp_kernel(
    const float* __restrict__ text_mem, const float* __restrict__ vis_mem,
    const float* __restrict__ vn, const float* __restrict__ tn,
    const int* __restrict__ slct, float* __restrict__ out,
    float* __restrict__ partials) {
  int b = blockIdx.x;
  int z = blockIdx.z;
  const float* mem  = (z == 0) ? text_mem : vis_mem;
  const float* feat = (z == 0) ? vn : tn;
  float* o = out + (size_t)z * NPAIR + (size_t)b * KP1;
  const int* srow = slct + b * KP1;
  __shared__ float4 sf[64];
  int t = threadIdx.x;
  if (t < 64) sf[t] = ((const float4*)(feat + b * EMB))[t];
  __syncthreads();
  int w = t >> 6, lane = t & 63;
  float4 f = sf[lane];
  int kbase = blockIdx.y * 256 + w * 64;
  int kend  = min(kbase + 64, KP1);
  float local = 0.f;
  int k = kbase;
  for (; k + 2 <= kend; k += 2) {
    int r0 = srow[k], r1 = srow[k + 1];
    float4 v0 = ((const float4*)(mem + (size_t)r0 * EMB))[lane];
    float4 v1 = ((const float4*)(mem + (size_t)r1 * EMB))[lane];
    float p0 = v0.x * f.x + v0.y * f.y + v0.z * f.z + v0.w * f.w;
    float p1 = v1.x * f.x + v1.y * f.y + v1.z * f.z + v1.w * f.w;
    for (int off = 32; off > 0; off >>= 1) {
      p0 += __shfl_down(p0, off, 64);
      p1 += __shfl_down(p1, off, 64);
    }
    if (lane == 0) {
      float e0 = __expf(p0 * INV_T);
      float e1 = __expf(p1 * INV_T);
      o[k] = e0; o[k + 1] = e1;
      local += e0 + e1;
    }
  }
  if (k < kend) {
    int r0 = srow[k];
    float4 v0 = ((const float4*)(mem + (size_t)r0 * EMB))[lane];
    float p0 = v0.x * f.x + v0.y * f.y + v0.z * f.z + v0.w * f.w;
    for (int off = 32; off > 0; off >>= 1) p0 += __shfl_down(p0, off, 64);
    if (lane == 0) { float e0 = __expf(p0 * INV_T); o[k] = e0; local += e0; }
  }
  __shared__ float red[4];
  if (lane == 0) red[w] = local;
  __syncthreads();
  if (t == 0)
    partials[((size_t)z * NBY + blockIdx.y) * BS + b] =
        red[0] + red[1] + red[2] + red[3];
}

__global__ __launch_bounds__(256) void reduce_z_kernel(
    const float* __restrict__ partials, float* __restrict__ zsum, int per_z) {
  int z = blockIdx.x;
  const float* p = partials + (size_t)z * per_z;
  float s = 0.f;
  for (int i = threadIdx.x; i < per_z; i += 256) s += p[i];
  for (int off = 32; off > 0; off >>= 1) s += __shfl_down(s, off, 64);
  __shared__ float red[4];
  if ((threadIdx.x & 63) == 0) red[threadIdx.x >> 6] = s;
  __syncthreads();
  if (threadIdx.x == 0) zsum[z] = red[0] + red[1] + red[2] + red[3];
}

__global__ __launch_bounds__(256) void copy2_kernel(
    const float4* __restrict__ src_a, float4* __restrict__ dst_a,
    const float4* __restrict__ src_b, float4* __restrict__ dst_b, long n4) {
  long i = (long)blockIdx.x * blockDim.x + threadIdx.x;
  long stride = (long)gridDim.x * blockDim.x;
  for (; i < 2 * n4; i += stride) {
    if (i < n4) dst_a[i] = src_a[i];
    else        dst_b[i - n4] = src_b[i - n4];
  }
}

// fallback in-place scale + EMA update
__global__ __launch_bounds__(256) void scale_update_kernel(
    float* __restrict__ out, const float* __restrict__ zsum,
    const float* __restrict__ vis_mem, const float* __restrict__ text_mem,
    const float* __restrict__ vn, const float* __restrict__ tn,
    const int* __restrict__ idx,
    float* __restrict__ out_vis, float* __restrict__ out_text) {
  int bid = blockIdx.x;
  if (bid < SCALE_BLKS) {
    int i = bid * 256 + threadIdx.x;
    if (i < 2 * NPAIR) {
      float Z = ((i < NPAIR) ? zsum[0] : zsum[1]) * ((float)NDATA / (float)NPAIR);
      out[i] = out[i] / Z;
    }
  } else {
    int bb = bid - SCALE_BLKS;
    int b = bb & 63;
    bool is_vis = bb < 64;
    int row = idx[b];
    for (int b2 = b + 1; b2 < BS; ++b2)
      if (idx[b2] == row) return;
    const float* mem  = (is_vis ? vis_mem : text_mem) + (size_t)row * EMB;
    const float* feat = (is_vis ? vn : tn) + b * EMB;
    float* dst = (is_vis ? out_vis : out_text) + (size_t)row * EMB;
    int t = threadIdx.x;
    float p = mem[t] * 0.5f + feat[t] * 0.5f;
    float s = p * p;
    for (int off = 32; off > 0; off >>= 1) s += __shfl_down(s, off, 64);
    __shared__ float red[4];
    if ((t & 63) == 0) red[t >> 6] = s;
    __syncthreads();
    float norm = sqrtf(red[0] + red[1] + red[2] + red[3]);
    dst[t] = p / fmaxf(norm, 1e-12f);
  }
}

// =============================================================================
extern "C" void kernel_launch(void* const* d_in, const int* in_sizes, int n_in,
                              void* d_out, int out_size, void* d_ws, size_t ws_size,
                              hipStream_t stream) {
  const float* vis_feat  = (const float*)d_in[0];
  const float* text_feat = (const float*)d_in[1];
  const float* vis_mem   = (const float*)d_in[2];
  const float* text_mem  = (const float*)d_in[3];
  const int*   slct      = (const int*)d_in[4];
  const int*   idx       = (const int*)d_in[5];

  float* out          = (float*)d_out;
  float* out_vis_mem  = out + (size_t)2 * NPAIR;
  float* out_text_mem = out_vis_mem + (size_t)NDATA * EMB;

  // workspace layout: zsum|counts contiguous (one memset); 16B alignment kept
  float*    ws     = (float*)d_ws;
  float*    zsum   = ws;                                   // 4 (padded)
  unsigned* counts = (unsigned*)(zsum + 4);                // NDATA
  unsigned* start  = counts + NDATA;                       // NDATA
  unsigned* bsum   = start + NDATA;                        // 256
  unsigned* bsum2  = bsum + 256;                           // 256 (scanned)
  unsigned* old    = bsum2 + 256;                          // NPAIR (reused: tmp0)
  unsigned* pairs  = old + NPAIR;                          // NPAIR
  float*    tmp1   = (float*)(pairs + NPAIR);              // NPAIR
  float*    vn     = tmp1 + NPAIR;                         // 16384
  float*    tn     = vn + BS * EMB;                        // 16384
  float*    tmp0   = (float*)old;                          // alias (old dead after scatter)
  size_t needed = ((size_t)(4 + 2 * NDATA + 512 + 3 * NPAIR) +
                   (size_t)(2 * BS * EMB)) * 4;

  if (ws_size >= needed) {
    // ---- fused path ----
    hipMemsetAsync(zsum, 0, (4 + NDATA) * sizeof(unsigned), stream);
    norm_hist_kernel<<<128 + (NPAIR + 255) / 256, 256, 0, stream>>>(
        vis_feat, text_feat, vn, tn, slct, counts, old);
    scan1_kernel<<<NB_SCAN, 256, 0, stream>>>(counts, start, bsum);
    scatter2_kernel<<<SSC_BLKS, 256, 0, stream>>>(slct, start, bsum, old, pairs,
                                                  bsum2);

    dim3 gF(NBLKF, 1, 2);
    fused_copy_dot_kernel<<<gF, 256, 0, stream>>>(
        text_mem, vis_mem, out_text_mem, out_vis_mem, vn, tn,
        counts, start, bsum2, pairs, tmp0, tmp1, zsum);

    scatter_scale_update_kernel<<<SSC_BLKS + 128, 256, 0, stream>>>(
        pairs, tmp0, tmp1, out, zsum, vis_mem, text_mem, vn, tn, idx,
        out_vis_mem, out_text_mem);
  } else {
    // ---- fallback: proven round-2 path ----
    norm_hist_kernel<<<128, 256, 0, stream>>>(
        vis_feat, text_feat, vn, tn, slct, counts, old);
    dim3 gB(BS, NBY, 2);
    dot_exp_kernel<<<gB, 256, 0, stream>>>(text_mem, vis_mem, vn, tn, slct, out,
                                           (float*)old);
    reduce_z_kernel<<<2, 256, 0, stream>>>((float*)old, zsum, NBY * BS);
    const long n4 = (long)NDATA * EMB / 4;
    copy2_kernel<<<8192, 256, 0, stream>>>(
        (const float4*)vis_mem,  (float4*)out_vis_mem,
        (const float4*)text_mem, (float4*)out_text_mem, n4);
    scale_update_kernel<<<SCALE_BLKS + 128, 256, 0, stream>>>(
        out, zsum, vis_mem, text_mem, vn, tn, idx, out_vis_mem, out_text_mem);
  }
}